// Round 1
// baseline (378.472 us; speedup 1.0000x reference)
//
#include <hip/hip_runtime.h>
#include <math.h>

// Problem constants
#define B_ 4
#define N_ 2048
#define D_ 512
#define H_ 8
#define DH_ 128
#define INNER_ 1024   // H_*DH_
#define W_ 32         // gaussian window half-width; exp(-33^2/(2*2.5^2)) ~ 1e-38

// ---------------------------------------------------------------------------
// FP32 tiled GEMM: C[M,N] = A[M,K] @ B[K,N], all row-major.
// BM=BN=128, BK=16, 256 threads, 8x8 microtile per thread.
// M,N divisible by 128; K divisible by 16 (holds for both GEMMs here).
// ---------------------------------------------------------------------------
#define BM 128
#define BN 128
#define BK 16

__global__ __launch_bounds__(256) void gemm_f32(
    const float* __restrict__ A, const float* __restrict__ Bm,
    float* __restrict__ C, int M, int N, int K)
{
    // +4 pad on As rows: row stride 132 floats = 528B (16B aligned, breaks
    // the c-major bank collision on transposed stores -> 2-way max = free)
    __shared__ float As[BK][BM + 4];
    __shared__ float Bs[BK][BN];

    const int tid = threadIdx.x;
    const int tx = tid & 15;   // col group (8 cols each)
    const int ty = tid >> 4;   // row group (8 rows each)
    const int bx = blockIdx.x; // N tile
    const int by = blockIdx.y; // M tile

    float acc[8][8];
    #pragma unroll
    for (int i = 0; i < 8; ++i)
        #pragma unroll
        for (int j = 0; j < 8; ++j) acc[i][j] = 0.f;

    for (int k0 = 0; k0 < K; k0 += BK) {
        // Load A tile (128 rows x 16 cols): 512 float4s, 2 per thread.
        #pragma unroll
        for (int it = 0; it < 2; ++it) {
            int idx = tid + it * 256;        // 0..511
            int row = idx >> 2;              // 0..127
            int c4  = (idx & 3) * 4;         // 0,4,8,12
            float4 av = *(const float4*)(A + (size_t)(by * BM + row) * K + k0 + c4);
            As[c4 + 0][row] = av.x;
            As[c4 + 1][row] = av.y;
            As[c4 + 2][row] = av.z;
            As[c4 + 3][row] = av.w;
        }
        // Load B tile (16 rows x 128 cols): 512 float4s, 2 per thread.
        #pragma unroll
        for (int it = 0; it < 2; ++it) {
            int idx = tid + it * 256;
            int row = idx >> 5;              // 0..15
            int c4  = (idx & 31) * 4;        // 0..124
            float4 bv = *(const float4*)(Bm + (size_t)(k0 + row) * N + bx * BN + c4);
            *(float4*)&Bs[row][c4] = bv;
        }
        __syncthreads();

        #pragma unroll
        for (int k = 0; k < BK; ++k) {
            float a[8], b[8];
            *(float4*)&a[0] = *(const float4*)&As[k][ty * 8];
            *(float4*)&a[4] = *(const float4*)&As[k][ty * 8 + 4];
            *(float4*)&b[0] = *(const float4*)&Bs[k][tx * 8];
            *(float4*)&b[4] = *(const float4*)&Bs[k][tx * 8 + 4];
            #pragma unroll
            for (int i = 0; i < 8; ++i)
                #pragma unroll
                for (int j = 0; j < 8; ++j)
                    acc[i][j] += a[i] * b[j];
        }
        __syncthreads();
    }

    // Epilogue
    #pragma unroll
    for (int i = 0; i < 8; ++i) {
        float* crow = C + (size_t)(by * BM + ty * 8 + i) * N + bx * BN + tx * 8;
        float4 o0 = make_float4(acc[i][0], acc[i][1], acc[i][2], acc[i][3]);
        float4 o1 = make_float4(acc[i][4], acc[i][5], acc[i][6], acc[i][7]);
        *(float4*)(crow)     = o0;
        *(float4*)(crow + 4) = o1;
    }
}

// ---------------------------------------------------------------------------
// Banded gaussian attention: attn[b,n,h*128+dh] =
//   sum_{m in [n-W, n+W] ∩ [0,N)} w(|n-m|) * v[b,m,h*128+dh] / sum_m w(|n-m|)
// Block handles one (b, h, 32-row n-tile). Stages 96 v-rows in LDS (48 KB).
// ---------------------------------------------------------------------------
#define TNA 32
#define ROWS (TNA + 2 * W_)   // 96

__global__ __launch_bounds__(256) void banded_attn(
    const float* __restrict__ v, const float* __restrict__ sigma,
    float* __restrict__ attn)
{
    __shared__ float vs[ROWS][DH_];     // 96*128*4 = 48 KB
    __shared__ float wtab[2 * W_ + 1];

    const int tid = threadIdx.x;
    const int n0 = blockIdx.x * TNA;
    const int h  = blockIdx.y;
    const int b  = blockIdx.z;

    if (tid <= 2 * W_) {
        float sig = sigma[h];
        float d = (float)(tid - W_);
        wtab[tid] = __expf(-d * d / (2.0f * sig * sig));
    }

    // Stage v rows [n0-W, n0+TNA+W) for this (b,h). 96*32=3072 float4s, 12/thread.
    const float* vbase = v + (size_t)b * N_ * INNER_ + h * DH_;
    #pragma unroll
    for (int it = 0; it < (ROWS * (DH_ / 4)) / 256; ++it) {
        int idx = tid + it * 256;
        int r  = idx >> 5;            // 0..95
        int c4 = (idx & 31) * 4;      // 0..124
        int m = n0 - W_ + r;
        float4 val = make_float4(0.f, 0.f, 0.f, 0.f);
        if (m >= 0 && m < N_) val = *(const float4*)(vbase + (size_t)m * INNER_ + c4);
        *(float4*)&vs[r][c4] = val;
    }
    __syncthreads();

    const int dh4 = (tid & 31) * 4;   // float4 column
    const int nst = tid >> 5;         // 0..7
    for (int nl = nst; nl < TNA; nl += 8) {
        int n = n0 + nl;
        float4 acc = make_float4(0.f, 0.f, 0.f, 0.f);
        float wsum = 0.f;
        #pragma unroll
        for (int j = 0; j <= 2 * W_; ++j) {
            int m = n - W_ + j;
            if (m < 0 || m >= N_) continue;
            float w = wtab[j];
            wsum += w;
            float4 vv = *(const float4*)&vs[nl + j][dh4];
            acc.x += w * vv.x; acc.y += w * vv.y;
            acc.z += w * vv.z; acc.w += w * vv.w;
        }
        float inv = 1.0f / wsum;      // wsum >= wtab[W_] = 1
        float4 o = make_float4(acc.x * inv, acc.y * inv, acc.z * inv, acc.w * inv);
        *(float4*)(attn + (size_t)(b * N_ + n) * INNER_ + h * DH_ + dh4) = o;
    }
}

// ---------------------------------------------------------------------------
extern "C" void kernel_launch(void* const* d_in, const int* in_sizes, int n_in,
                              void* d_out, int out_size, void* d_ws, size_t ws_size,
                              hipStream_t stream) {
    const float* x     = (const float*)d_in[0];  // [B,N,D]
    const float* Wg    = (const float*)d_in[1];  // [D, INNER]
    const float* Wout  = (const float*)d_in[2];  // [INNER, D]
    const float* sigma = (const float*)d_in[3];  // [H]
    float* out = (float*)d_out;                  // [B,N,D] f32

    const int M = B_ * N_;                       // 8192
    float* v    = (float*)d_ws;                  // [M, INNER] = 32 MB
    float* attn = v + (size_t)M * INNER_;        // [M, INNER] = 32 MB

    dim3 blk(256);

    // v = x @ Wg   : [8192,512]@[512,1024]
    gemm_f32<<<dim3(INNER_ / BN, M / BM), blk, 0, stream>>>(x, Wg, v, M, INNER_, D_);

    // attn = corr @ v (banded gaussian blur per head, row-normalized)
    banded_attn<<<dim3(N_ / TNA, H_, B_), blk, 0, stream>>>(v, sigma, attn);

    // out = attn @ Wout : [8192,1024]@[1024,512]
    gemm_f32<<<dim3(D_ / BN, M / BM), blk, 0, stream>>>(attn, Wout, out, M, D_, INNER_);
}

// Round 3
// 197.596 us; speedup vs baseline: 1.9154x; 1.9154x over previous
//
#include <hip/hip_runtime.h>
#include <hip/hip_bf16.h>
#include <math.h>

// Problem constants
#define B_ 4
#define N_ 2048
#define D_ 512
#define H_ 8
#define DH_ 128
#define INNER_ 1024   // H_*DH_
#define W_ 32         // gaussian window half-width; exp(-33^2/(2*2.5^2)) ~ 1e-38
#define M_ (B_ * N_)  // 8192

typedef __attribute__((ext_vector_type(8))) short short8;   // 8 bf16 = 4 VGPRs
typedef __attribute__((ext_vector_type(4))) float floatx4;  // MFMA C/D

typedef const __attribute__((address_space(1))) char* gcp;
typedef __attribute__((address_space(3))) char* lcp;

// ---------------------------------------------------------------------------
// bf16 MFMA GEMM: C[M,N] (fp32) = A[M,K] (bf16, row-major) @ Bt[N,K]^T (bf16).
// 128x128 block tile, BK=32, 256 threads = 4 waves (2x2), 64x64 per wave via
// 4x4 grid of 16x16x32 MFMA. global_load_lds width=16 staging; XOR chunk
// swizzle on the GLOBAL source so ds_read_b128 lands 2-way (free) not 8-way.
// M,N % 128 == 0, K % 32 == 0.
// ---------------------------------------------------------------------------
__global__ __launch_bounds__(256) void gemm_bf16_mfma(
    const __hip_bfloat16* __restrict__ A, const __hip_bfloat16* __restrict__ Bt,
    float* __restrict__ C, int M, int N, int K)
{
    __shared__ __hip_bfloat16 Asm[128 * 32];  // 8 KB, row = 64 B (4 chunks of 16 B)
    __shared__ __hip_bfloat16 Bsm[128 * 32];  // 8 KB

    const int tid  = threadIdx.x;
    const int lane = tid & 63;
    const int w    = tid >> 6;       // 0..3
    const int wm   = w >> 1;         // 0..1
    const int wn   = w & 1;          // 0..1
    const int bm   = blockIdx.y;
    const int bn   = blockIdx.x;

    const int kh = lane >> 4;        // 0..3: which K-chunk of 8 bf16
    const int ml = lane & 15;        // row-in-tile for A/B fragments

    floatx4 acc[4][4];
    #pragma unroll
    for (int i = 0; i < 4; ++i)
        #pragma unroll
        for (int j = 0; j < 4; ++j) acc[i][j] = (floatx4){0.f, 0.f, 0.f, 0.f};

    const char* Ab = (const char*)(A + (size_t)(bm * 128) * K);
    const char* Bb = (const char*)(Bt + (size_t)(bn * 128) * K);
    const size_t rowstride = (size_t)K * 2;  // bytes

    for (int k0 = 0; k0 < K; k0 += 32) {
        // ---- stage A,B tiles: each thread moves 2x16B per matrix ----
        #pragma unroll
        for (int it = 0; it < 2; ++it) {
            int o = w * 1024 + it * 4096 + lane * 16;  // LDS byte (linear, lane*16)
            int r = o >> 6;                            // tile row 0..127
            int s = (o >> 4) & 3;                      // LDS chunk slot 0..3
            int c = (s - (r >> 1)) & 3;                // global chunk (XOR-ish swizzle)
            size_t goff = (size_t)r * rowstride + (size_t)k0 * 2 + c * 16;
            __builtin_amdgcn_global_load_lds((gcp)(Ab + goff), (lcp)((char*)Asm + o), 16, 0, 0);
            __builtin_amdgcn_global_load_lds((gcp)(Bb + goff), (lcp)((char*)Bsm + o), 16, 0, 0);
        }
        __syncthreads();

        // ---- fragments + MFMA ----
        const short* As = (const short*)Asm;
        const short* Bs = (const short*)Bsm;
        short8 af[4], bf[4];
        #pragma unroll
        for (int t = 0; t < 4; ++t) {
            int ra = wm * 64 + t * 16 + ml;
            int rb = wn * 64 + t * 16 + ml;
            int sa = ((ra >> 1) + kh) & 3;   // de-swizzle: slot holding chunk kh
            int sb = ((rb >> 1) + kh) & 3;
            af[t] = *(const short8*)(As + ra * 32 + sa * 8);
            bf[t] = *(const short8*)(Bs + rb * 32 + sb * 8);
        }
        #pragma unroll
        for (int i = 0; i < 4; ++i)
            #pragma unroll
            for (int j = 0; j < 4; ++j)
                acc[i][j] = __builtin_amdgcn_mfma_f32_16x16x32_bf16(af[i], bf[j], acc[i][j], 0, 0, 0);
        __syncthreads();
    }

    // ---- epilogue: C/D layout col=lane&15, row=(lane>>4)*4+reg ----
    const int rq = lane >> 4;  // 0..3
    const int cl = lane & 15;
    #pragma unroll
    for (int i = 0; i < 4; ++i) {
        #pragma unroll
        for (int j = 0; j < 4; ++j) {
            #pragma unroll
            for (int r = 0; r < 4; ++r) {
                int row = bm * 128 + wm * 64 + i * 16 + rq * 4 + r;
                int col = bn * 128 + wn * 64 + j * 16 + cl;
                C[(size_t)row * N + col] = acc[i][j][r];
            }
        }
    }
}

// ---------------------------------------------------------------------------
// fp32 -> bf16 cast (8 elems/thread)
// ---------------------------------------------------------------------------
__global__ __launch_bounds__(256) void cast_bf16(
    const float* __restrict__ src, __hip_bfloat16* __restrict__ dst, int n8)
{
    int i = blockIdx.x * 256 + threadIdx.x;
    if (i >= n8) return;
    const float4* s = (const float4*)src + i * 2;
    float4 a = s[0], b = s[1];
    __hip_bfloat16 o[8] = {
        __float2bfloat16(a.x), __float2bfloat16(a.y), __float2bfloat16(a.z), __float2bfloat16(a.w),
        __float2bfloat16(b.x), __float2bfloat16(b.y), __float2bfloat16(b.z), __float2bfloat16(b.w)};
    *(short8*)(dst + (size_t)i * 8) = *(short8*)o;
}

// ---------------------------------------------------------------------------
// fp32 [R,C] -> bf16 [C,R] transpose+cast. R,C % 32 == 0. block (32,8)
// ---------------------------------------------------------------------------
__global__ __launch_bounds__(256) void transpose_cast(
    const float* __restrict__ src, __hip_bfloat16* __restrict__ dst, int R, int Cn)
{
    __shared__ float t[32][33];
    int c0 = blockIdx.x * 32, r0 = blockIdx.y * 32;
    int lx = threadIdx.x, ly = threadIdx.y;
    #pragma unroll
    for (int i = 0; i < 32; i += 8)
        t[ly + i][lx] = src[(size_t)(r0 + ly + i) * Cn + c0 + lx];
    __syncthreads();
    #pragma unroll
    for (int i = 0; i < 32; i += 8)
        dst[(size_t)(c0 + ly + i) * R + r0 + lx] = __float2bfloat16(t[lx][ly + i]);
}

// ---------------------------------------------------------------------------
// Banded gaussian attention: bf16 output (feeds GEMM2 A-operand).
// ---------------------------------------------------------------------------
#define TNA 32
#define ROWS (TNA + 2 * W_)   // 96

struct bf16x4s { __hip_bfloat16 a, b, c, d; };

__global__ __launch_bounds__(256) void banded_attn(
    const float* __restrict__ v, const float* __restrict__ sigma,
    __hip_bfloat16* __restrict__ attn)
{
    __shared__ float vs[ROWS][DH_];     // 48 KB
    __shared__ float wtab[2 * W_ + 1];

    const int tid = threadIdx.x;
    const int n0 = blockIdx.x * TNA;
    const int h  = blockIdx.y;
    const int b  = blockIdx.z;

    if (tid <= 2 * W_) {
        float sig = sigma[h];
        float d = (float)(tid - W_);
        wtab[tid] = __expf(-d * d / (2.0f * sig * sig));
    }

    const float* vbase = v + (size_t)b * N_ * INNER_ + h * DH_;
    #pragma unroll
    for (int it = 0; it < (ROWS * (DH_ / 4)) / 256; ++it) {
        int idx = tid + it * 256;
        int r  = idx >> 5;
        int c4 = (idx & 31) * 4;
        int m = n0 - W_ + r;
        float4 val = make_float4(0.f, 0.f, 0.f, 0.f);
        if (m >= 0 && m < N_) val = *(const float4*)(vbase + (size_t)m * INNER_ + c4);
        *(float4*)&vs[r][c4] = val;
    }
    __syncthreads();

    const int dh4 = (tid & 31) * 4;
    const int nst = tid >> 5;
    for (int nl = nst; nl < TNA; nl += 8) {
        int n = n0 + nl;
        float4 acc = make_float4(0.f, 0.f, 0.f, 0.f);
        float wsum = 0.f;
        #pragma unroll
        for (int j = 0; j <= 2 * W_; ++j) {
            int m = n - W_ + j;
            if (m < 0 || m >= N_) continue;
            float w = wtab[j];
            wsum += w;
            float4 vv = *(const float4*)&vs[nl + j][dh4];
            acc.x += w * vv.x; acc.y += w * vv.y;
            acc.z += w * vv.z; acc.w += w * vv.w;
        }
        float inv = 1.0f / wsum;
        bf16x4s o = { __float2bfloat16(acc.x * inv), __float2bfloat16(acc.y * inv),
                      __float2bfloat16(acc.z * inv), __float2bfloat16(acc.w * inv) };
        *(bf16x4s*)(attn + (size_t)(b * N_ + n) * INNER_ + h * DH_ + dh4) = o;
    }
}

// ---------------------------------------------------------------------------
extern "C" void kernel_launch(void* const* d_in, const int* in_sizes, int n_in,
                              void* d_out, int out_size, void* d_ws, size_t ws_size,
                              hipStream_t stream) {
    const float* x     = (const float*)d_in[0];  // [B,N,D] = [M_, D_]
    const float* Wg    = (const float*)d_in[1];  // [D_, INNER_]
    const float* Wout  = (const float*)d_in[2];  // [INNER_, D_]
    const float* sigma = (const float*)d_in[3];  // [H_]
    float* out = (float*)d_out;                  // [M_, D_] fp32

    // Workspace layout (bytes): 58 MB total
    char* ws = (char*)d_ws;
    __hip_bfloat16* x_bf   = (__hip_bfloat16*)ws;                          // 8 MB  [M_, D_]
    __hip_bfloat16* Wg_t   = (__hip_bfloat16*)(ws + (((size_t)8) << 20));  // 1 MB  [INNER_, D_]
    __hip_bfloat16* Wout_t = (__hip_bfloat16*)(ws + (((size_t)9) << 20));  // 1 MB  [D_, INNER_]
    float*          v      = (float*)(ws + (((size_t)10) << 20));          // 32 MB [M_, INNER_]
    __hip_bfloat16* attn   = (__hip_bfloat16*)(ws + (((size_t)42) << 20)); // 16 MB [M_, INNER_]

    // Prologue: casts/transposes (independent, memory-bound)
    cast_bf16<<<dim3((M_ * D_ / 8 + 255) / 256), dim3(256), 0, stream>>>(x, x_bf, M_ * D_ / 8);
    transpose_cast<<<dim3(INNER_ / 32, D_ / 32), dim3(32, 8), 0, stream>>>(Wg, Wg_t, D_, INNER_);
    transpose_cast<<<dim3(D_ / 32, INNER_ / 32), dim3(32, 8), 0, stream>>>(Wout, Wout_t, INNER_, D_);

    // v = x @ Wg : [8192,512] @ [512,1024] -> fp32
    gemm_bf16_mfma<<<dim3(INNER_ / 128, M_ / 128), dim3(256), 0, stream>>>(
        x_bf, Wg_t, v, M_, INNER_, D_);

    // attn = banded gaussian blur (row-normalized), bf16 out
    banded_attn<<<dim3(N_ / TNA, H_, B_), dim3(256), 0, stream>>>(v, sigma, attn);

    // out = attn @ Wout : [8192,1024] @ [1024,512] -> fp32
    gemm_bf16_mfma<<<dim3(D_ / 128, M_ / 128), dim3(256), 0, stream>>>(
        attn, Wout_t, out, M_, D_, INNER_);
}

// Round 5
// 142.589 us; speedup vs baseline: 2.6543x; 1.3858x over previous
//
#include <hip/hip_runtime.h>
#include <hip/hip_bf16.h>
#include <math.h>

// Problem constants
#define B_ 4
#define N_ 2048
#define D_ 512
#define H_ 8
#define DH_ 128
#define INNER_ 1024   // H_*DH_
#define W_ 32         // gaussian window half-width; exp(-33^2/(2*2.5^2)) ~ 1e-38
#define M_ (B_ * N_)  // 8192

typedef __attribute__((ext_vector_type(8))) short short8;   // 8 bf16 = 4 VGPRs
typedef __attribute__((ext_vector_type(4))) float floatx4;  // MFMA C/D

typedef const __attribute__((address_space(1))) char* gcp;
typedef __attribute__((address_space(3))) char* lcp;

__device__ __forceinline__ float bf16hi_to_f(unsigned u) {
    union { unsigned u; float f; } c; c.u = u; return c.f;
}

// ---------------------------------------------------------------------------
// bf16 MFMA GEMM: C[M,N] = A[M,K] (bf16 rm) @ Bt[N,K]^T (bf16). OutT fp32/bf16.
// 128x128 tile, BK=32, 4 waves, 4x4 16x16x32 MFMA per wave; global_load_lds
// width=16; XOR chunk swizzle on the GLOBAL source -> conflict-free ds_read.
// ---------------------------------------------------------------------------
template <typename OutT>
__global__ __launch_bounds__(256) void gemm_bf16_mfma(
    const __hip_bfloat16* __restrict__ A, const __hip_bfloat16* __restrict__ Bt,
    OutT* __restrict__ C, int M, int N, int K)
{
    __shared__ __hip_bfloat16 Asm[128 * 32];  // 8 KB
    __shared__ __hip_bfloat16 Bsm[128 * 32];  // 8 KB

    const int tid  = threadIdx.x;
    const int lane = tid & 63;
    const int w    = tid >> 6;
    const int wm   = w >> 1;
    const int wn   = w & 1;
    const int bm   = blockIdx.y;
    const int bn   = blockIdx.x;

    const int kh = lane >> 4;
    const int ml = lane & 15;

    floatx4 acc[4][4];
    #pragma unroll
    for (int i = 0; i < 4; ++i)
        #pragma unroll
        for (int j = 0; j < 4; ++j) acc[i][j] = (floatx4){0.f, 0.f, 0.f, 0.f};

    const char* Ab = (const char*)(A + (size_t)(bm * 128) * K);
    const char* Bb = (const char*)(Bt + (size_t)(bn * 128) * K);
    const size_t rowstride = (size_t)K * 2;

    for (int k0 = 0; k0 < K; k0 += 32) {
        #pragma unroll
        for (int it = 0; it < 2; ++it) {
            int o = w * 1024 + it * 4096 + lane * 16;
            int r = o >> 6;
            int s = (o >> 4) & 3;
            int c = (s - (r >> 1)) & 3;
            size_t goff = (size_t)r * rowstride + (size_t)k0 * 2 + c * 16;
            __builtin_amdgcn_global_load_lds((gcp)(Ab + goff), (lcp)((char*)Asm + o), 16, 0, 0);
            __builtin_amdgcn_global_load_lds((gcp)(Bb + goff), (lcp)((char*)Bsm + o), 16, 0, 0);
        }
        __syncthreads();

        const short* As = (const short*)Asm;
        const short* Bs = (const short*)Bsm;
        short8 af[4], bf[4];
        #pragma unroll
        for (int t = 0; t < 4; ++t) {
            int ra = wm * 64 + t * 16 + ml;
            int rb = wn * 64 + t * 16 + ml;
            int sa = ((ra >> 1) + kh) & 3;
            int sb = ((rb >> 1) + kh) & 3;
            af[t] = *(const short8*)(As + ra * 32 + sa * 8);
            bf[t] = *(const short8*)(Bs + rb * 32 + sb * 8);
        }
        #pragma unroll
        for (int i = 0; i < 4; ++i)
            #pragma unroll
            for (int j = 0; j < 4; ++j)
                acc[i][j] = __builtin_amdgcn_mfma_f32_16x16x32_bf16(af[i], bf[j], acc[i][j], 0, 0, 0);
        __syncthreads();
    }

    const int rq = lane >> 4;
    const int cl = lane & 15;
    #pragma unroll
    for (int i = 0; i < 4; ++i) {
        #pragma unroll
        for (int j = 0; j < 4; ++j) {
            #pragma unroll
            for (int r = 0; r < 4; ++r) {
                int row = bm * 128 + wm * 64 + i * 16 + rq * 4 + r;
                int col = bn * 128 + wn * 64 + j * 16 + cl;
                if constexpr (sizeof(OutT) == 2)
                    C[(size_t)row * N + col] = __float2bfloat16(acc[i][j][r]);
                else
                    C[(size_t)row * N + col] = acc[i][j][r];
            }
        }
    }
}

// ---------------------------------------------------------------------------
// fp32 -> bf16 cast (8 elems/thread)
// ---------------------------------------------------------------------------
__global__ __launch_bounds__(256) void cast_bf16(
    const float* __restrict__ src, __hip_bfloat16* __restrict__ dst, int n8)
{
    int i = blockIdx.x * 256 + threadIdx.x;
    if (i >= n8) return;
    const float4* s = (const float4*)src + i * 2;
    float4 a = s[0], b = s[1];
    __hip_bfloat16 o[8] = {
        __float2bfloat16(a.x), __float2bfloat16(a.y), __float2bfloat16(a.z), __float2bfloat16(a.w),
        __float2bfloat16(b.x), __float2bfloat16(b.y), __float2bfloat16(b.z), __float2bfloat16(b.w)};
    *(short8*)(dst + (size_t)i * 8) = *(short8*)o;
}

// ---------------------------------------------------------------------------
// fp32 [R,C] -> bf16 [C,R] transpose+cast. block (32,8)
// ---------------------------------------------------------------------------
__global__ __launch_bounds__(256) void transpose_cast(
    const float* __restrict__ src, __hip_bfloat16* __restrict__ dst, int R, int Cn)
{
    __shared__ float t[32][33];
    int c0 = blockIdx.x * 32, r0 = blockIdx.y * 32;
    int lx = threadIdx.x, ly = threadIdx.y;
    #pragma unroll
    for (int i = 0; i < 32; i += 8)
        t[ly + i][lx] = src[(size_t)(r0 + ly + i) * Cn + c0 + lx];
    __syncthreads();
    #pragma unroll
    for (int i = 0; i < 32; i += 8)
        dst[(size_t)(c0 + ly + i) * R + r0 + lx] = __float2bfloat16(t[lx][ly + i]);
}

// ---------------------------------------------------------------------------
// Banded gaussian blur v2: bf16 in / bf16 out, fp32 accumulate.
// Block = one (b,h) x 64-row tile. Stage 128 rows x 128 ch bf16 = 32 KB.
// Thread = 4 channels x 8 consecutive rows; rolling 8-reg weight window:
// one 8B LDS tap read feeds 32 FMAs; branch-free interior.
// ---------------------------------------------------------------------------
#define TNA 64
#define ROWSB (TNA + 2 * W_)   // 128

struct bf16x4s { __hip_bfloat16 a, b, c, d; };

__global__ __launch_bounds__(256) void banded_attn2(
    const __hip_bfloat16* __restrict__ v, const float* __restrict__ sigma,
    __hip_bfloat16* __restrict__ attn)
{
    __shared__ __hip_bfloat16 vs[ROWSB][DH_];  // 32 KB
    __shared__ float wtab[2 * W_ + 1];         // 65
    __shared__ float winv[TNA];

    const int tid = threadIdx.x;
    const int n0 = blockIdx.x * TNA;
    const int h  = blockIdx.y;
    const int b  = blockIdx.z;

    // ---- phase A: stage v rows (zero-padded) + weight table ----
    const __hip_bfloat16* vbase = v + (size_t)b * N_ * INNER_ + h * DH_;
    #pragma unroll
    for (int it = 0; it < 8; ++it) {
        int idx = tid + it * 256;     // 0..2047
        int r = idx >> 4;             // 0..127
        int g = idx & 15;             // 8-ch group
        int m = n0 - W_ + r;
        int4 val = make_int4(0, 0, 0, 0);
        if (m >= 0 && m < N_) val = *(const int4*)(vbase + (size_t)m * INNER_ + g * 8);
        *(int4*)&vs[r][g * 8] = val;
    }
    if (tid <= 2 * W_) {
        float sig = sigma[h];
        float d = (float)(tid - W_);
        wtab[tid] = __expf(-d * d / (2.0f * sig * sig));
    }
    __syncthreads();

    // ---- phase B: per-row normalizer ----
    if (tid < TNA) {
        int n = n0 + tid;
        float ws = 0.f;
        #pragma unroll
        for (int j = 0; j <= 2 * W_; ++j) {
            int m = n - W_ + j;
            ws += (m >= 0 && m < N_) ? wtab[j] : 0.f;
        }
        winv[tid] = 1.0f / ws;
    }
    __syncthreads();

    // ---- main: rolling-window banded accumulation ----
    const int cg = tid & 31;   // 4-channel group
    const int rg = tid >> 5;   // 0..7 (8 rows each)

    float4 acc[8];
    #pragma unroll
    for (int r = 0; r < 8; ++r) acc[r] = make_float4(0.f, 0.f, 0.f, 0.f);
    float wreg[8] = {0.f, 0.f, 0.f, 0.f, 0.f, 0.f, 0.f, 0.f};

    const unsigned* vrow0 = (const unsigned*)&vs[rg * 8][cg * 4];

    // l = tap offset from thread's first row; output row r needs taps
    // l = r .. r+64 with weight wtab[l-r]. Max l = 7+64 = 71 -> bound 72.
    #pragma unroll 8
    for (int l = 0; l < 2 * W_ + 8; ++l) {   // 0..71
        wreg[l & 7] = (l <= 2 * W_) ? wtab[l] : 0.f;   // wave-uniform select
        const unsigned* p = vrow0 + (size_t)l * (DH_ / 2);
        unsigned r0 = p[0], r1 = p[1];
        float4 vv;
        vv.x = bf16hi_to_f(r0 << 16);
        vv.y = bf16hi_to_f(r0 & 0xffff0000u);
        vv.z = bf16hi_to_f(r1 << 16);
        vv.w = bf16hi_to_f(r1 & 0xffff0000u);
        #pragma unroll
        for (int r = 0; r < 8; ++r) {
            float wgt = wreg[(l - r) & 7];
            acc[r].x += wgt * vv.x; acc[r].y += wgt * vv.y;
            acc[r].z += wgt * vv.z; acc[r].w += wgt * vv.w;
        }
    }

    // ---- store ----
    #pragma unroll
    for (int r = 0; r < 8; ++r) {
        int nl = rg * 8 + r;
        float s = winv[nl];
        bf16x4s o = { __float2bfloat16(acc[r].x * s), __float2bfloat16(acc[r].y * s),
                      __float2bfloat16(acc[r].z * s), __float2bfloat16(acc[r].w * s) };
        *(bf16x4s*)(attn + ((size_t)b * N_ + n0 + nl) * INNER_ + h * DH_ + cg * 4) = o;
    }
}

// ---------------------------------------------------------------------------
extern "C" void kernel_launch(void* const* d_in, const int* in_sizes, int n_in,
                              void* d_out, int out_size, void* d_ws, size_t ws_size,
                              hipStream_t stream) {
    const float* x     = (const float*)d_in[0];  // [M_, D_]
    const float* Wg    = (const float*)d_in[1];  // [D_, INNER_]
    const float* Wout  = (const float*)d_in[2];  // [INNER_, D_]
    const float* sigma = (const float*)d_in[3];  // [H_]
    float* out = (float*)d_out;                  // [M_, D_] fp32

    // Workspace layout: 42 MB
    char* ws = (char*)d_ws;
    __hip_bfloat16* x_bf   = (__hip_bfloat16*)ws;                           // 8 MB
    __hip_bfloat16* Wg_t   = (__hip_bfloat16*)(ws + (((size_t)8)  << 20));  // 1 MB
    __hip_bfloat16* Wout_t = (__hip_bfloat16*)(ws + (((size_t)9)  << 20));  // 1 MB
    __hip_bfloat16* v_bf   = (__hip_bfloat16*)(ws + (((size_t)10) << 20));  // 16 MB [M_, INNER_]
    __hip_bfloat16* attn   = (__hip_bfloat16*)(ws + (((size_t)26) << 20));  // 16 MB [M_, INNER_]

    cast_bf16<<<dim3((M_ * D_ / 8 + 255) / 256), dim3(256), 0, stream>>>(x, x_bf, M_ * D_ / 8);
    transpose_cast<<<dim3(INNER_ / 32, D_ / 32), dim3(32, 8), 0, stream>>>(Wg, Wg_t, D_, INNER_);
    transpose_cast<<<dim3(D_ / 32, INNER_ / 32), dim3(32, 8), 0, stream>>>(Wout, Wout_t, INNER_, D_);

    // v = x @ Wg -> bf16
    gemm_bf16_mfma<__hip_bfloat16><<<dim3(INNER_ / 128, M_ / 128), dim3(256), 0, stream>>>(
        x_bf, Wg_t, v_bf, M_, INNER_, D_);

    // attn = row-normalized gaussian blur of v (banded)
    banded_attn2<<<dim3(N_ / TNA, H_, B_), dim3(256), 0, stream>>>(v_bf, sigma, attn);

    // out = attn @ Wout -> fp32
    gemm_bf16_mfma<float><<<dim3(D_ / 128, M_ / 128), dim3(256), 0, stream>>>(
        attn, Wout_t, out, M_, D_, INNER_);
}

// Round 6
// 137.304 us; speedup vs baseline: 2.7565x; 1.0385x over previous
//
#include <hip/hip_runtime.h>
#include <hip/hip_bf16.h>
#include <math.h>

// Problem constants
#define B_ 4
#define N_ 2048
#define D_ 512
#define H_ 8
#define DH_ 128
#define INNER_ 1024   // H_*DH_
#define W_ 32         // gaussian window half-width; exp(-33^2/(2*2.5^2)) ~ 1e-38
#define M_ (B_ * N_)  // 8192

typedef __attribute__((ext_vector_type(8))) short short8;   // 8 bf16 = 4 VGPRs
typedef __attribute__((ext_vector_type(4))) float floatx4;  // MFMA C/D

typedef const __attribute__((address_space(1))) char* gcp;
typedef __attribute__((address_space(3))) char* lcp;

__device__ __forceinline__ float bf16hi_to_f(unsigned u) {
    union { unsigned u; float f; } c; c.u = u; return c.f;
}

// ---------------------------------------------------------------------------
// bf16 MFMA GEMM, small-tile/high-occupancy variant for short-K problems:
// C[M,N] = A[M,K] (bf16 rm) @ Bt[N,K]^T (bf16). OutT fp32/bf16.
// 64x64 block tile, BK=64, 256 threads = 4 waves (2x2), 32x32 per wave via
// 2x2 grid of 16x16x32 MFMA x 2 k-halves. global_load_lds width=16 staging
// with XOR-row chunk swizzle on the GLOBAL source -> 2-way (free) ds_read.
// LDS = 16 KB -> 8 blocks/CU; grids of 1024-2048 blocks = 4-8/CU so staging
// of one block overlaps MFMA of others (the m114 wave-overlap effect).
// M,N % 64 == 0, K % 64 == 0.
// ---------------------------------------------------------------------------
template <typename OutT>
__global__ __launch_bounds__(256, 4) void gemm_bf16_mfma64(
    const __hip_bfloat16* __restrict__ A, const __hip_bfloat16* __restrict__ Bt,
    OutT* __restrict__ C, int M, int N, int K)
{
    __shared__ __hip_bfloat16 Asm[64 * 64];  // 8 KB; row = 128 B = 8 chunks of 16 B
    __shared__ __hip_bfloat16 Bsm[64 * 64];  // 8 KB

    const int tid  = threadIdx.x;
    const int lane = tid & 63;
    const int w    = tid >> 6;
    const int wm   = w >> 1;         // 0..1
    const int wn   = w & 1;          // 0..1
    const int bm   = blockIdx.y;
    const int bn   = blockIdx.x;

    const int kh = lane >> 4;        // 0..3: 16-B chunk within 64-B k-half
    const int ml = lane & 15;

    floatx4 acc[2][2];
    #pragma unroll
    for (int i = 0; i < 2; ++i)
        #pragma unroll
        for (int j = 0; j < 2; ++j) acc[i][j] = (floatx4){0.f, 0.f, 0.f, 0.f};

    const char* Ab = (const char*)(A + (size_t)(bm * 64) * K);
    const char* Bb = (const char*)(Bt + (size_t)(bn * 64) * K);
    const size_t rowstride = (size_t)K * 2;

    for (int k0 = 0; k0 < K; k0 += 64) {
        // ---- stage A,B 64x64 tiles: 2 x 16 B per thread per matrix ----
        #pragma unroll
        for (int it = 0; it < 2; ++it) {
            int o = it * 4096 + tid * 16;   // linear LDS byte; base wave-uniform + lane*16
            int r = o >> 7;                 // tile row 0..63
            int s = (o >> 4) & 7;           // LDS slot 0..7
            int c = s ^ (r & 7);            // global chunk (XOR-row swizzle)
            size_t goff = (size_t)r * rowstride + (size_t)k0 * 2 + c * 16;
            __builtin_amdgcn_global_load_lds((gcp)(Ab + goff), (lcp)((char*)Asm + o), 16, 0, 0);
            __builtin_amdgcn_global_load_lds((gcp)(Bb + goff), (lcp)((char*)Bsm + o), 16, 0, 0);
        }
        __syncthreads();

        // ---- fragments (de-swizzled) + MFMA ----
        const short* As = (const short*)Asm;
        const short* Bs = (const short*)Bsm;
        short8 af[2][2], bf[2][2];
        #pragma unroll
        for (int t = 0; t < 2; ++t) {
            int ra = wm * 32 + t * 16 + ml;
            int rb = wn * 32 + t * 16 + ml;
            #pragma unroll
            for (int kk = 0; kk < 2; ++kk) {
                int ch = kk * 4 + kh;
                af[t][kk] = *(const short8*)(As + ra * 64 + ((ch ^ (ra & 7)) * 8));
                bf[t][kk] = *(const short8*)(Bs + rb * 64 + ((ch ^ (rb & 7)) * 8));
            }
        }
        #pragma unroll
        for (int kk = 0; kk < 2; ++kk)
            #pragma unroll
            for (int i = 0; i < 2; ++i)
                #pragma unroll
                for (int j = 0; j < 2; ++j)
                    acc[i][j] = __builtin_amdgcn_mfma_f32_16x16x32_bf16(
                        af[i][kk], bf[j][kk], acc[i][j], 0, 0, 0);
        __syncthreads();
    }

    // ---- epilogue: C/D layout col=lane&15, row=(lane>>4)*4+reg ----
    const int rq = lane >> 4;
    const int cl = lane & 15;
    #pragma unroll
    for (int i = 0; i < 2; ++i) {
        #pragma unroll
        for (int j = 0; j < 2; ++j) {
            #pragma unroll
            for (int r = 0; r < 4; ++r) {
                int row = bm * 64 + wm * 32 + i * 16 + rq * 4 + r;
                int col = bn * 64 + wn * 32 + j * 16 + cl;
                if constexpr (sizeof(OutT) == 2)
                    C[(size_t)row * N + col] = __float2bfloat16(acc[i][j][r]);
                else
                    C[(size_t)row * N + col] = acc[i][j][r];
            }
        }
    }
}

// ---------------------------------------------------------------------------
// fp32 -> bf16 cast (8 elems/thread)
// ---------------------------------------------------------------------------
__global__ __launch_bounds__(256) void cast_bf16(
    const float* __restrict__ src, __hip_bfloat16* __restrict__ dst, int n8)
{
    int i = blockIdx.x * 256 + threadIdx.x;
    if (i >= n8) return;
    const float4* s = (const float4*)src + i * 2;
    float4 a = s[0], b = s[1];
    __hip_bfloat16 o[8] = {
        __float2bfloat16(a.x), __float2bfloat16(a.y), __float2bfloat16(a.z), __float2bfloat16(a.w),
        __float2bfloat16(b.x), __float2bfloat16(b.y), __float2bfloat16(b.z), __float2bfloat16(b.w)};
    *(short8*)(dst + (size_t)i * 8) = *(short8*)o;
}

// ---------------------------------------------------------------------------
// fp32 [R,C] -> bf16 [C,R] transpose+cast. block (32,8)
// ---------------------------------------------------------------------------
__global__ __launch_bounds__(256) void transpose_cast(
    const float* __restrict__ src, __hip_bfloat16* __restrict__ dst, int R, int Cn)
{
    __shared__ float t[32][33];
    int c0 = blockIdx.x * 32, r0 = blockIdx.y * 32;
    int lx = threadIdx.x, ly = threadIdx.y;
    #pragma unroll
    for (int i = 0; i < 32; i += 8)
        t[ly + i][lx] = src[(size_t)(r0 + ly + i) * Cn + c0 + lx];
    __syncthreads();
    #pragma unroll
    for (int i = 0; i < 32; i += 8)
        dst[(size_t)(c0 + ly + i) * R + r0 + lx] = __float2bfloat16(t[lx][ly + i]);
}

// ---------------------------------------------------------------------------
// Banded gaussian blur: bf16 in / bf16 out, fp32 accumulate.
// Block = one (b,h) x 64-row tile. Stage 128 rows x 128 ch bf16 = 32 KB.
// Thread = 4 channels x 8 consecutive rows; rolling 8-reg weight window:
// one 8B LDS tap read feeds 32 FMAs; branch-free interior.
// ---------------------------------------------------------------------------
#define TNA 64
#define ROWSB (TNA + 2 * W_)   // 128

struct bf16x4s { __hip_bfloat16 a, b, c, d; };

__global__ __launch_bounds__(256) void banded_attn2(
    const __hip_bfloat16* __restrict__ v, const float* __restrict__ sigma,
    __hip_bfloat16* __restrict__ attn)
{
    __shared__ __hip_bfloat16 vs[ROWSB][DH_];  // 32 KB
    __shared__ float wtab[2 * W_ + 1];         // 65
    __shared__ float winv[TNA];

    const int tid = threadIdx.x;
    const int n0 = blockIdx.x * TNA;
    const int h  = blockIdx.y;
    const int b  = blockIdx.z;

    // ---- phase A: stage v rows (zero-padded) + weight table ----
    const __hip_bfloat16* vbase = v + (size_t)b * N_ * INNER_ + h * DH_;
    #pragma unroll
    for (int it = 0; it < 8; ++it) {
        int idx = tid + it * 256;     // 0..2047
        int r = idx >> 4;             // 0..127
        int g = idx & 15;             // 8-ch group
        int m = n0 - W_ + r;
        int4 val = make_int4(0, 0, 0, 0);
        if (m >= 0 && m < N_) val = *(const int4*)(vbase + (size_t)m * INNER_ + g * 8);
        *(int4*)&vs[r][g * 8] = val;
    }
    if (tid <= 2 * W_) {
        float sig = sigma[h];
        float d = (float)(tid - W_);
        wtab[tid] = __expf(-d * d / (2.0f * sig * sig));
    }
    __syncthreads();

    // ---- phase B: per-row normalizer ----
    if (tid < TNA) {
        int n = n0 + tid;
        float ws = 0.f;
        #pragma unroll
        for (int j = 0; j <= 2 * W_; ++j) {
            int m = n - W_ + j;
            ws += (m >= 0 && m < N_) ? wtab[j] : 0.f;
        }
        winv[tid] = 1.0f / ws;
    }
    __syncthreads();

    // ---- main: rolling-window banded accumulation ----
    const int cg = tid & 31;   // 4-channel group
    const int rg = tid >> 5;   // 0..7 (8 rows each)

    float4 acc[8];
    #pragma unroll
    for (int r = 0; r < 8; ++r) acc[r] = make_float4(0.f, 0.f, 0.f, 0.f);
    float wreg[8] = {0.f, 0.f, 0.f, 0.f, 0.f, 0.f, 0.f, 0.f};

    const unsigned* vrow0 = (const unsigned*)&vs[rg * 8][cg * 4];

    // Output row r needs taps l = r .. r+64 with weight wtab[l-r]; max l = 71.
    #pragma unroll 8
    for (int l = 0; l < 2 * W_ + 8; ++l) {   // 0..71
        wreg[l & 7] = (l <= 2 * W_) ? wtab[l] : 0.f;   // wave-uniform select
        const unsigned* p = vrow0 + (size_t)l * (DH_ / 2);
        unsigned r0 = p[0], r1 = p[1];
        float4 vv;
        vv.x = bf16hi_to_f(r0 << 16);
        vv.y = bf16hi_to_f(r0 & 0xffff0000u);
        vv.z = bf16hi_to_f(r1 << 16);
        vv.w = bf16hi_to_f(r1 & 0xffff0000u);
        #pragma unroll
        for (int r = 0; r < 8; ++r) {
            float wgt = wreg[(l - r) & 7];
            acc[r].x += wgt * vv.x; acc[r].y += wgt * vv.y;
            acc[r].z += wgt * vv.z; acc[r].w += wgt * vv.w;
        }
    }

    // ---- store ----
    #pragma unroll
    for (int r = 0; r < 8; ++r) {
        int nl = rg * 8 + r;
        float s = winv[nl];
        bf16x4s o = { __float2bfloat16(acc[r].x * s), __float2bfloat16(acc[r].y * s),
                      __float2bfloat16(acc[r].z * s), __float2bfloat16(acc[r].w * s) };
        *(bf16x4s*)(attn + ((size_t)b * N_ + n0 + nl) * INNER_ + h * DH_ + cg * 4) = o;
    }
}

// ---------------------------------------------------------------------------
extern "C" void kernel_launch(void* const* d_in, const int* in_sizes, int n_in,
                              void* d_out, int out_size, void* d_ws, size_t ws_size,
                              hipStream_t stream) {
    const float* x     = (const float*)d_in[0];  // [M_, D_]
    const float* Wg    = (const float*)d_in[1];  // [D_, INNER_]
    const float* Wout  = (const float*)d_in[2];  // [INNER_, D_]
    const float* sigma = (const float*)d_in[3];  // [H_]
    float* out = (float*)d_out;                  // [M_, D_] fp32

    // Workspace layout: 42 MB
    char* ws = (char*)d_ws;
    __hip_bfloat16* x_bf   = (__hip_bfloat16*)ws;                           // 8 MB
    __hip_bfloat16* Wg_t   = (__hip_bfloat16*)(ws + (((size_t)8)  << 20));  // 1 MB
    __hip_bfloat16* Wout_t = (__hip_bfloat16*)(ws + (((size_t)9)  << 20));  // 1 MB
    __hip_bfloat16* v_bf   = (__hip_bfloat16*)(ws + (((size_t)10) << 20));  // 16 MB [M_, INNER_]
    __hip_bfloat16* attn   = (__hip_bfloat16*)(ws + (((size_t)26) << 20));  // 16 MB [M_, INNER_]

    cast_bf16<<<dim3((M_ * D_ / 8 + 255) / 256), dim3(256), 0, stream>>>(x, x_bf, M_ * D_ / 8);
    transpose_cast<<<dim3(INNER_ / 32, D_ / 32), dim3(32, 8), 0, stream>>>(Wg, Wg_t, D_, INNER_);
    transpose_cast<<<dim3(D_ / 32, INNER_ / 32), dim3(32, 8), 0, stream>>>(Wout, Wout_t, INNER_, D_);

    // v = x @ Wg -> bf16 : grid 16x128 = 2048 blocks (8/CU)
    gemm_bf16_mfma64<__hip_bfloat16><<<dim3(INNER_ / 64, M_ / 64), dim3(256), 0, stream>>>(
        x_bf, Wg_t, v_bf, M_, INNER_, D_);

    // attn = row-normalized gaussian blur of v (banded)
    banded_attn2<<<dim3(N_ / TNA, H_, B_), dim3(256), 0, stream>>>(v_bf, sigma, attn);

    // out = attn @ Wout -> fp32 : grid 8x128 = 1024 blocks (4/CU)
    gemm_bf16_mfma64<float><<<dim3(D_ / 64, M_ / 64), dim3(256), 0, stream>>>(
        attn, Wout_t, out, M_, D_, INNER_);
}

// Round 7
// 136.951 us; speedup vs baseline: 2.7636x; 1.0026x over previous
//
#include <hip/hip_runtime.h>
#include <hip/hip_bf16.h>
#include <math.h>

// Problem constants
#define B_ 4
#define N_ 2048
#define D_ 512
#define H_ 8
#define DH_ 128
#define INNER_ 1024   // H_*DH_
#define W_ 32         // gaussian window half-width; exp(-33^2/(2*2.5^2)) ~ 1e-38
#define M_ (B_ * N_)  // 8192

typedef __attribute__((ext_vector_type(8))) short short8;   // 8 bf16 = 4 VGPRs
typedef __attribute__((ext_vector_type(4))) float floatx4;  // MFMA C/D

typedef const __attribute__((address_space(1))) char* gcp;
typedef __attribute__((address_space(3))) char* lcp;

__device__ __forceinline__ float bf16hi_to_f(unsigned u) {
    union { unsigned u; float f; } c; c.u = u; return c.f;
}

// ---------------------------------------------------------------------------
// bf16 MFMA GEMM, 64x64 tile / BK=64 / 256 thr (4 waves 2x2, 32x32 each).
// global_load_lds width=16 with XOR-row chunk swizzle (conflict-light reads).
// NEW: epilogue stages the 64x64 fp32 C-tile through LDS and stores 16 B
// per thread (1-KB segments per wave-inst) instead of scalar stores.
// M,N % 64 == 0, K % 64 == 0.
// ---------------------------------------------------------------------------
template <typename OutT>
__global__ __launch_bounds__(256, 4) void gemm_bf16_mfma64(
    const __hip_bfloat16* __restrict__ A, const __hip_bfloat16* __restrict__ Bt,
    OutT* __restrict__ C, int M, int N, int K)
{
    __shared__ char smem[16384];                     // Asm 8K | Bsm 8K ; reused as Cs
    __hip_bfloat16* Asm = (__hip_bfloat16*)smem;
    __hip_bfloat16* Bsm = (__hip_bfloat16*)(smem + 8192);

    const int tid  = threadIdx.x;
    const int lane = tid & 63;
    const int w    = tid >> 6;
    const int wm   = w >> 1;         // 0..1
    const int wn   = w & 1;          // 0..1
    const int bm   = blockIdx.y;
    const int bn   = blockIdx.x;

    const int kh = lane >> 4;        // 0..3
    const int ml = lane & 15;

    floatx4 acc[2][2];
    #pragma unroll
    for (int i = 0; i < 2; ++i)
        #pragma unroll
        for (int j = 0; j < 2; ++j) acc[i][j] = (floatx4){0.f, 0.f, 0.f, 0.f};

    const char* Ab = (const char*)(A + (size_t)(bm * 64) * K);
    const char* Bb = (const char*)(Bt + (size_t)(bn * 64) * K);
    const size_t rowstride = (size_t)K * 2;

    for (int k0 = 0; k0 < K; k0 += 64) {
        #pragma unroll
        for (int it = 0; it < 2; ++it) {
            int o = it * 4096 + tid * 16;   // LDS byte; wave-uniform base + lane*16
            int r = o >> 7;                 // tile row 0..63
            int s = (o >> 4) & 7;           // LDS slot 0..7
            int c = s ^ (r & 7);            // global chunk (XOR-row swizzle)
            size_t goff = (size_t)r * rowstride + (size_t)k0 * 2 + c * 16;
            __builtin_amdgcn_global_load_lds((gcp)(Ab + goff), (lcp)((char*)Asm + o), 16, 0, 0);
            __builtin_amdgcn_global_load_lds((gcp)(Bb + goff), (lcp)((char*)Bsm + o), 16, 0, 0);
        }
        __syncthreads();

        const short* As = (const short*)Asm;
        const short* Bs = (const short*)Bsm;
        short8 af[2][2], bf[2][2];
        #pragma unroll
        for (int t = 0; t < 2; ++t) {
            int ra = wm * 32 + t * 16 + ml;
            int rb = wn * 32 + t * 16 + ml;
            #pragma unroll
            for (int kk = 0; kk < 2; ++kk) {
                int ch = kk * 4 + kh;
                af[t][kk] = *(const short8*)(As + ra * 64 + ((ch ^ (ra & 7)) * 8));
                bf[t][kk] = *(const short8*)(Bs + rb * 64 + ((ch ^ (rb & 7)) * 8));
            }
        }
        #pragma unroll
        for (int kk = 0; kk < 2; ++kk)
            #pragma unroll
            for (int i = 0; i < 2; ++i)
                #pragma unroll
                for (int j = 0; j < 2; ++j)
                    acc[i][j] = __builtin_amdgcn_mfma_f32_16x16x32_bf16(
                        af[i][kk], bf[j][kk], acc[i][j], 0, 0, 0);
        __syncthreads();
    }

    // ---- epilogue: stage C-tile (64x64 fp32 = 16 KB) in LDS, vector store ----
    float* Cs = (float*)smem;   // safe: loop ended with __syncthreads()
    const int rq = lane >> 4;
    const int cl = lane & 15;
    #pragma unroll
    for (int i = 0; i < 2; ++i)
        #pragma unroll
        for (int j = 0; j < 2; ++j)
            #pragma unroll
            for (int r = 0; r < 4; ++r)
                Cs[(wm * 32 + i * 16 + rq * 4 + r) * 64 + wn * 32 + j * 16 + cl] = acc[i][j][r];
    __syncthreads();

    if constexpr (sizeof(OutT) == 2) {
        // 256 threads x 8 floats -> 8 bf16 (16 B store), one pass
        int row = tid >> 3;              // 0..63  (wait: 256/8=32 rows/pass -> 2 passes)
        #pragma unroll
        for (int p = 0; p < 2; ++p) {
            int idx = p * 256 + tid;     // 0..511
            int rr = idx >> 3;           // 0..63
            int cc = (idx & 7) * 8;      // 0..56
            const float* src = Cs + rr * 64 + cc;
            __hip_bfloat16 o[8];
            #pragma unroll
            for (int e = 0; e < 8; ++e) o[e] = __float2bfloat16(src[e]);
            *(short8*)((__hip_bfloat16*)C + (size_t)(bm * 64 + rr) * N + bn * 64 + cc) = *(short8*)o;
        }
        (void)row;
    } else {
        // 256 threads x 4 floats (16 B), 4 passes
        #pragma unroll
        for (int p = 0; p < 4; ++p) {
            int idx = p * 256 + tid;     // 0..1023
            int rr = idx >> 4;           // 0..63
            int cc = (idx & 15) * 4;     // 0..60
            float4 vv = *(const float4*)(Cs + rr * 64 + cc);
            *(float4*)((float*)C + (size_t)(bm * 64 + rr) * N + bn * 64 + cc) = vv;
        }
    }
}

// ---------------------------------------------------------------------------
// Fused prologue: job by flat block id.
//   blocks [0, 2048)        : x fp32 -> bf16 cast (8 elems/thread)
//   blocks [2048, 2560)     : Wg  [512,1024]  -> Wg_t  [1024,512] bf16
//   blocks [2560, 3072)     : Wout [1024,512] -> Wout_t [512,1024] bf16
// ---------------------------------------------------------------------------
__device__ __forceinline__ void transpose32(
    const float* __restrict__ src, __hip_bfloat16* __restrict__ dst,
    int R, int Cn, int rt, int ct, int tid)
{
    __shared__ float t[32][33];
    int c0 = ct * 32, r0 = rt * 32;
    int lx = tid & 31, ly = tid >> 5;   // 32 x 8
    #pragma unroll
    for (int i = 0; i < 32; i += 8)
        t[ly + i][lx] = src[(size_t)(r0 + ly + i) * Cn + c0 + lx];
    __syncthreads();
    #pragma unroll
    for (int i = 0; i < 32; i += 8)
        dst[(size_t)(c0 + ly + i) * R + r0 + lx] = __float2bfloat16(t[lx][ly + i]);
}

__global__ __launch_bounds__(256) void prep(
    const float* __restrict__ x, const float* __restrict__ Wg,
    const float* __restrict__ Wout, __hip_bfloat16* __restrict__ x_bf,
    __hip_bfloat16* __restrict__ Wg_t, __hip_bfloat16* __restrict__ Wout_t)
{
    const int bid = blockIdx.x;
    const int tid = threadIdx.x;
    if (bid < 2048) {
        int i = bid * 256 + tid;         // n8 = 2048*256
        const float4* s = (const float4*)x + (size_t)i * 2;
        float4 a = s[0], b = s[1];
        __hip_bfloat16 o[8] = {
            __float2bfloat16(a.x), __float2bfloat16(a.y), __float2bfloat16(a.z), __float2bfloat16(a.w),
            __float2bfloat16(b.x), __float2bfloat16(b.y), __float2bfloat16(b.z), __float2bfloat16(b.w)};
        *(short8*)(x_bf + (size_t)i * 8) = *(short8*)o;
    } else if (bid < 2560) {
        int id2 = bid - 2048;            // Wg: R=512, Cn=1024 -> 32 ct x 16 rt
        transpose32(Wg, Wg_t, D_, INNER_, id2 >> 5, id2 & 31, tid);
    } else {
        int id2 = bid - 2560;            // Wout: R=1024, Cn=512 -> 16 ct x 32 rt
        transpose32(Wout, Wout_t, INNER_, D_, id2 >> 4, id2 & 15, tid);
    }
}

// ---------------------------------------------------------------------------
// Banded gaussian blur v3: bf16 in/out, fp32 accumulate.
// Block = (b, h, ch-half, 64-row tile): 128 rows x 64 ch staged = 16 KB.
// Thread = 4 ch x 4 consecutive rows; 4-deep rolling weight window;
// one 8-B LDS read feeds 16 FMAs. Grid = 32*16*4 = 2048 blocks (8/CU).
// ---------------------------------------------------------------------------
#define TNA 64
#define ROWSB (TNA + 2 * W_)   // 128
#define CHB 64                 // channels per block

struct bf16x4s { __hip_bfloat16 a, b, c, d; };

__global__ __launch_bounds__(256) void banded_attn3(
    const __hip_bfloat16* __restrict__ v, const float* __restrict__ sigma,
    __hip_bfloat16* __restrict__ attn)
{
    __shared__ __hip_bfloat16 vs[ROWSB][CHB];  // 16 KB
    __shared__ float wtab[2 * W_ + 1];
    __shared__ float winv[TNA];

    const int tid = threadIdx.x;
    const int n0  = blockIdx.x * TNA;
    const int h   = blockIdx.y >> 1;
    const int ch0 = (blockIdx.y & 1) * CHB;
    const int b   = blockIdx.z;

    // ---- stage 128 rows x 64 ch (zero-padded) ----
    const __hip_bfloat16* vbase = v + (size_t)b * N_ * INNER_ + h * DH_ + ch0;
    #pragma unroll
    for (int it = 0; it < 4; ++it) {
        int idx = tid + it * 256;     // 0..1023
        int r = idx >> 3;             // 0..127
        int g = idx & 7;              // 8-ch (16 B) group
        int m = n0 - W_ + r;
        int4 val = make_int4(0, 0, 0, 0);
        if (m >= 0 && m < N_) val = *(const int4*)(vbase + (size_t)m * INNER_ + g * 8);
        *(int4*)&vs[r][g * 8] = val;
    }
    if (tid <= 2 * W_) {
        float sig = sigma[h];
        float d = (float)(tid - W_);
        wtab[tid] = __expf(-d * d / (2.0f * sig * sig));
    }
    __syncthreads();

    if (tid < TNA) {
        int n = n0 + tid;
        float ws = 0.f;
        #pragma unroll
        for (int j = 0; j <= 2 * W_; ++j) {
            int m = n - W_ + j;
            ws += (m >= 0 && m < N_) ? wtab[j] : 0.f;
        }
        winv[tid] = 1.0f / ws;
    }
    __syncthreads();

    // ---- main: 4-row x 4-ch rolling-window accumulation ----
    const int cg = tid & 15;   // 4-ch group
    const int rg = tid >> 4;   // 0..15 (4 rows each)

    float4 acc[4];
    #pragma unroll
    for (int r = 0; r < 4; ++r) acc[r] = make_float4(0.f, 0.f, 0.f, 0.f);
    float wreg[4] = {0.f, 0.f, 0.f, 0.f};

    const unsigned* vrow0 = (const unsigned*)&vs[rg * 4][cg * 4];

    // Output row r (0..3) needs taps l = r .. r+64, weight wtab[l-r]; max l=67.
    #pragma unroll 4
    for (int l = 0; l < 2 * W_ + 4; ++l) {   // 0..67
        wreg[l & 3] = (l <= 2 * W_) ? wtab[l] : 0.f;
        const unsigned* p = vrow0 + (size_t)l * (CHB / 2);
        unsigned r0 = p[0], r1 = p[1];
        float4 vv;
        vv.x = bf16hi_to_f(r0 << 16);
        vv.y = bf16hi_to_f(r0 & 0xffff0000u);
        vv.z = bf16hi_to_f(r1 << 16);
        vv.w = bf16hi_to_f(r1 & 0xffff0000u);
        #pragma unroll
        for (int r = 0; r < 4; ++r) {
            float wgt = wreg[(l - r) & 3];
            acc[r].x += wgt * vv.x; acc[r].y += wgt * vv.y;
            acc[r].z += wgt * vv.z; acc[r].w += wgt * vv.w;
        }
    }

    #pragma unroll
    for (int r = 0; r < 4; ++r) {
        int nl = rg * 4 + r;
        float s = winv[nl];
        bf16x4s o = { __float2bfloat16(acc[r].x * s), __float2bfloat16(acc[r].y * s),
                      __float2bfloat16(acc[r].z * s), __float2bfloat16(acc[r].w * s) };
        *(bf16x4s*)(attn + ((size_t)b * N_ + n0 + nl) * INNER_ + h * DH_ + ch0 + cg * 4) = o;
    }
}

// ---------------------------------------------------------------------------
extern "C" void kernel_launch(void* const* d_in, const int* in_sizes, int n_in,
                              void* d_out, int out_size, void* d_ws, size_t ws_size,
                              hipStream_t stream) {
    const float* x     = (const float*)d_in[0];  // [M_, D_]
    const float* Wg    = (const float*)d_in[1];  // [D_, INNER_]
    const float* Wout  = (const float*)d_in[2];  // [INNER_, D_]
    const float* sigma = (const float*)d_in[3];  // [H_]
    float* out = (float*)d_out;                  // [M_, D_] fp32

    // Workspace layout: 42 MB
    char* ws = (char*)d_ws;
    __hip_bfloat16* x_bf   = (__hip_bfloat16*)ws;                           // 8 MB
    __hip_bfloat16* Wg_t   = (__hip_bfloat16*)(ws + (((size_t)8)  << 20));  // 1 MB
    __hip_bfloat16* Wout_t = (__hip_bfloat16*)(ws + (((size_t)9)  << 20));  // 1 MB
    __hip_bfloat16* v_bf   = (__hip_bfloat16*)(ws + (((size_t)10) << 20));  // 16 MB [M_, INNER_]
    __hip_bfloat16* attn   = (__hip_bfloat16*)(ws + (((size_t)26) << 20));  // 16 MB [M_, INNER_]

    // Fused prologue: 3072 blocks
    prep<<<dim3(3072), dim3(256), 0, stream>>>(x, Wg, Wout, x_bf, Wg_t, Wout_t);

    // v = x @ Wg -> bf16 : grid 16x128 = 2048 blocks (8/CU)
    gemm_bf16_mfma64<__hip_bfloat16><<<dim3(INNER_ / 64, M_ / 64), dim3(256), 0, stream>>>(
        x_bf, Wg_t, v_bf, M_, INNER_, D_);

    // attn = row-normalized gaussian blur of v (banded): 2048 blocks
    banded_attn3<<<dim3(N_ / TNA, H_ * 2, B_), dim3(256), 0, stream>>>(v_bf, sigma, attn);

    // out = attn @ Wout -> fp32 : grid 8x128 = 1024 blocks (4/CU)
    gemm_bf16_mfma64<float><<<dim3(D_ / 64, M_ / 64), dim3(256), 0, stream>>>(
        attn, Wout_t, out, M_, D_, INNER_);
}